// Round 2
// baseline (1141.201 us; speedup 1.0000x reference)
//
#include <hip/hip_runtime.h>

typedef unsigned short u16;
typedef unsigned int u32;
typedef __bf16 v8bf __attribute__((ext_vector_type(8)));
typedef _Float16 f16;
typedef _Float16 v8hf __attribute__((ext_vector_type(8)));
typedef float f32x4 __attribute__((ext_vector_type(4)));

#define BATCH 16384
#define IN_DIM 700
#define IN_PAD 704
#define H_ENC 2048
#define LATENT 512
#define H_DEC 2048
#define OUT_DIM 700
#define OUT_PAD 768
#define NUM_EMB 1024

// scales: A-operands x16, B-operands x64 (keeps split-hi out of fp16 subnormal range)
#define SA 16.0f
#define SB 64.0f
#define INV_SASB 9.765625e-4f   // 2^-10 exact
#define LO_SCALE 2048.0f
#define INV_LO 4.8828125e-4f    // 2^-11 exact

__device__ __forceinline__ float b2f(u16 u) {
    u32 x = ((u32)u) << 16;
    return __uint_as_float(x);
}
__device__ __forceinline__ u16 f2b(float f) {  // round-to-nearest-even
    u32 x = __float_as_uint(f);
    u32 r = x + 0x7fffu + ((x >> 16) & 1u);
    return (u16)(r >> 16);
}
__device__ __forceinline__ void splitf(float v, f16& hi, f16& lo) {
    hi = (f16)v;                       // RNE
    lo = (f16)((v - (float)hi) * LO_SCALE);  // v-hi exact (Sterbenz); scaled to normal range
}

// async global->LDS, 16B per lane; lds dest wave-uniform base (+lane*16 by HW)
__device__ __forceinline__ void gld16(const void* g, void* s) {
    __builtin_amdgcn_global_load_lds((const __attribute__((address_space(1))) void*)g,
                                     (__attribute__((address_space(3))) void*)s, 16, 0, 0);
}

// ---------------- conversion kernels ----------------

__global__ void split_x(const float* __restrict__ x, f16* __restrict__ xh, f16* __restrict__ xl) {
    int idx = blockIdx.x * 256 + threadIdx.x;
    if (idx >= BATCH * IN_PAD) return;
    int r = idx / IN_PAD, c = idx - r * IN_PAD;
    float v = (c < IN_DIM) ? x[(size_t)r * IN_DIM + c] * SA : 0.f;
    f16 hi, lo;
    splitf(v, hi, lo);
    xh[idx] = hi;
    xl[idx] = lo;
}

// W:[K][N] fp32 row-major -> Th/Tl:[N][Kp] f16 split of W*scale (zero padded); Tf optional raw fp32
__global__ void transpose_split(const float* __restrict__ W, f16* __restrict__ Th,
                                f16* __restrict__ Tl, float* __restrict__ Tf,
                                int K, int N, int Kp, float scale) {
    __shared__ float tile[32][33];
    int kb = blockIdx.x * 32, nb = blockIdx.y * 32;
    int tx = threadIdx.x, ty = threadIdx.y;
    for (int i = ty; i < 32; i += 8) {
        int k = kb + i, n = nb + tx;
        tile[i][tx] = (k < K && n < N) ? W[(size_t)k * N + n] : 0.f;
    }
    __syncthreads();
    for (int i = ty; i < 32; i += 8) {
        int n = nb + i, kk = kb + tx;
        if (n < N && kk < Kp) {
            float v = tile[tx][i];
            if (Tf) Tf[(size_t)n * Kp + kk] = v;
            f16 hi, lo;
            splitf(v * scale, hi, lo);
            Th[(size_t)n * Kp + kk] = hi;
            Tl[(size_t)n * Kp + kk] = lo;
        }
    }
}

// W:[K][N] fp32 -> WT:[Np][Kp] bf16 (zero padded) — decoder weights
__global__ void transpose_pad(const float* __restrict__ W, u16* __restrict__ WT,
                              int K, int N, int Kp, int Np) {
    __shared__ float tile[32][33];
    int kb = blockIdx.x * 32, nb = blockIdx.y * 32;
    int tx = threadIdx.x, ty = threadIdx.y;
    for (int i = ty; i < 32; i += 8) {
        int k = kb + i, n = nb + tx;
        tile[i][tx] = (k < K && n < N) ? W[(size_t)k * N + n] : 0.f;
    }
    __syncthreads();
    for (int i = ty; i < 32; i += 8) {
        int n = nb + i, k = kb + tx;
        if (n < Np && k < Kp) WT[(size_t)n * Kp + k] = f2b(tile[tx][i]);
    }
}

__global__ void enorm_k(const float* __restrict__ emb, float* __restrict__ enorm) {
    int n = blockIdx.x * 256 + threadIdx.x;
    if (n >= NUM_EMB) return;
    double s = 0.0;  // exact-grade |e_j|^2
    for (int k = 0; k < LATENT; ++k) {
        float v = emb[(size_t)k * NUM_EMB + n];
        s += (double)v * (double)v;
    }
    enorm[n] = (float)s;
}

__global__ void zero_loss(float* p) {
    if (threadIdx.x == 0) p[0] = 0.f;
}

// ---------------- fp16x2 high-precision GEMM: C = act((A*SA) @ (B*SB)^T)/2^10 + bias ----------------
// A split: Ah + 2^-11*Al ; B split: Bh + 2^-11*Bl (both [rows][K] f16, pre-scaled)
// acc0 = Ah@Bh ; acc1 = Ah@Bl + Al@Bh ; v = (acc0 + 2^-11*acc1) * 2^-10 + bias
// MODE 1: leaky, store split(v*SA) to Oh/Ol      (h for next precise stage)
// MODE 2: store split(v*SA) to Oh/Ol             (z)
// MODE 3: raw f32 store to Of                    (distance dots)
template <int MODE>
__global__ __launch_bounds__(256) void gemm2(
    const f16* __restrict__ Ahg, const f16* __restrict__ Alg,
    const f16* __restrict__ Bhg, const f16* __restrict__ Blg,
    const float* __restrict__ bias,
    f16* __restrict__ Oh, f16* __restrict__ Ol, float* __restrict__ Of,
    int N, int K) {
    __shared__ f16 Ah[128 * 32];
    __shared__ f16 Al[128 * 32];
    __shared__ f16 Bh[128 * 32];
    __shared__ f16 Bl[128 * 32];
    const int w = threadIdx.x >> 6;
    const int lane = threadIdx.x & 63;
    const int bm = blockIdx.y * 128;
    const int bn = blockIdx.x * 128;

    const int srow = w * 32 + (lane >> 2);
    const int scol = (lane & 3) * 8;
    const f16* AhG = Ahg + (size_t)(bm + srow) * K + scol;
    const f16* AlG = Alg + (size_t)(bm + srow) * K + scol;
    const f16* BhG = Bhg + (size_t)(bn + srow) * K + scol;
    const f16* BlG = Blg + (size_t)(bn + srow) * K + scol;
    f16* AhW = &Ah[(w * 32) * 32];
    f16* AlW = &Al[(w * 32) * 32];
    f16* BhW = &Bh[(w * 32) * 32];
    f16* BlW = &Bl[(w * 32) * 32];

    const int mBase = (w >> 1) * 64;
    const int nBase = (w & 1) * 64;

    f32x4 acc0[4][4], acc1[4][4];
    const f32x4 z4 = {0.f, 0.f, 0.f, 0.f};
#pragma unroll
    for (int a = 0; a < 4; ++a)
#pragma unroll
        for (int b = 0; b < 4; ++b) { acc0[a][b] = z4; acc1[a][b] = z4; }

    for (int k0 = 0; k0 < K; k0 += 32) {
        gld16(AhG + k0, AhW);
        gld16(AhG + k0 + (size_t)16 * K, AhW + 16 * 32);
        gld16(AlG + k0, AlW);
        gld16(AlG + k0 + (size_t)16 * K, AlW + 16 * 32);
        gld16(BhG + k0, BhW);
        gld16(BhG + k0 + (size_t)16 * K, BhW + 16 * 32);
        gld16(BlG + k0, BlW);
        gld16(BlG + k0 + (size_t)16 * K, BlW + 16 * 32);
        __syncthreads();
        v8hf ah[4], al[4], bh[4], bl[4];
#pragma unroll
        for (int t = 0; t < 4; ++t) {
            const int ro = (t * 16 + (lane & 15)) * 32 + (lane >> 4) * 8;
            ah[t] = *(const v8hf*)&Ah[(mBase)*32 + ro];
            al[t] = *(const v8hf*)&Al[(mBase)*32 + ro];
            bh[t] = *(const v8hf*)&Bh[(nBase)*32 + ro];
            bl[t] = *(const v8hf*)&Bl[(nBase)*32 + ro];
        }
#pragma unroll
        for (int tm = 0; tm < 4; ++tm)
#pragma unroll
            for (int tn = 0; tn < 4; ++tn)
                acc0[tm][tn] = __builtin_amdgcn_mfma_f32_16x16x32_f16(ah[tm], bh[tn], acc0[tm][tn], 0, 0, 0);
#pragma unroll
        for (int tm = 0; tm < 4; ++tm)
#pragma unroll
            for (int tn = 0; tn < 4; ++tn)
                acc1[tm][tn] = __builtin_amdgcn_mfma_f32_16x16x32_f16(ah[tm], bl[tn], acc1[tm][tn], 0, 0, 0);
#pragma unroll
        for (int tm = 0; tm < 4; ++tm)
#pragma unroll
            for (int tn = 0; tn < 4; ++tn)
                acc1[tm][tn] = __builtin_amdgcn_mfma_f32_16x16x32_f16(al[tm], bh[tn], acc1[tm][tn], 0, 0, 0);
        __syncthreads();
    }

    // C/D frag layout col=lane&15, row=(lane>>4)*4+r
#pragma unroll
    for (int tm = 0; tm < 4; ++tm) {
        const int r0 = bm + mBase + tm * 16 + (lane >> 4) * 4;
#pragma unroll
        for (int tn = 0; tn < 4; ++tn) {
            const int c = bn + nBase + tn * 16 + (lane & 15);
            const float bvv = (MODE == 3) ? 0.f : bias[c];
#pragma unroll
            for (int r = 0; r < 4; ++r) {
                float v = (acc0[tm][tn][r] + acc1[tm][tn][r] * INV_LO) * INV_SASB + bvv;
                if (MODE == 1) v = (v >= 0.f) ? v : 0.2f * v;
                const size_t o = (size_t)(r0 + r) * N + c;
                if (MODE == 3) {
                    Of[o] = v;
                } else {
                    f16 hi, lo;
                    splitf(v * SA, hi, lo);
                    Oh[o] = hi;
                    Ol[o] = lo;
                }
            }
        }
    }
}

// ---------------- bf16 GEMM (decoder), C = act(A @ B^T + bias) ----------------
// MODE 0: f32 store, +bias, predicated c<Nreal (recon). MODE 1: bf16 store, +bias, leaky.
template <int MODE>
__global__ __launch_bounds__(256) void gemm_bt(
    const u16* __restrict__ A, const u16* __restrict__ B,
    const float* __restrict__ bias, void* __restrict__ Cout,
    int N, int K, int ldc, int Nreal) {
    __shared__ u16 As[128 * 32];
    __shared__ u16 Bs[128 * 32];
    const int w = threadIdx.x >> 6;
    const int lane = threadIdx.x & 63;
    const int bm = blockIdx.y * 128;
    const int bn = blockIdx.x * 128;

    const int srow = w * 32 + (lane >> 2);
    const int scol = (lane & 3) * 8;
    const u16* Ag = A + (size_t)(bm + srow) * K + scol;
    const u16* Bg = B + (size_t)(bn + srow) * K + scol;
    u16* AsW = &As[(w * 32) * 32];
    u16* BsW = &Bs[(w * 32) * 32];

    const int mBase = (w >> 1) * 64;
    const int nBase = (w & 1) * 64;

    f32x4 acc[4][4];
    const f32x4 z4 = {0.f, 0.f, 0.f, 0.f};
#pragma unroll
    for (int a = 0; a < 4; ++a)
#pragma unroll
        for (int b = 0; b < 4; ++b) acc[a][b] = z4;

    for (int k0 = 0; k0 < K; k0 += 32) {
        gld16(Ag + k0, AsW);
        gld16(Ag + k0 + (size_t)16 * K, AsW + 16 * 32);
        gld16(Bg + k0, BsW);
        gld16(Bg + k0 + (size_t)16 * K, BsW + 16 * 32);
        __syncthreads();
        v8bf af[4], bv[4];
#pragma unroll
        for (int t = 0; t < 4; ++t) {
            af[t] = *(const v8bf*)&As[(mBase + t * 16 + (lane & 15)) * 32 + (lane >> 4) * 8];
            bv[t] = *(const v8bf*)&Bs[(nBase + t * 16 + (lane & 15)) * 32 + (lane >> 4) * 8];
        }
#pragma unroll
        for (int tm = 0; tm < 4; ++tm)
#pragma unroll
            for (int tn = 0; tn < 4; ++tn)
                acc[tm][tn] = __builtin_amdgcn_mfma_f32_16x16x32_bf16(af[tm], bv[tn], acc[tm][tn], 0, 0, 0);
        __syncthreads();
    }

#pragma unroll
    for (int tm = 0; tm < 4; ++tm) {
        const int r0 = bm + mBase + tm * 16 + (lane >> 4) * 4;
#pragma unroll
        for (int tn = 0; tn < 4; ++tn) {
            const int c = bn + nBase + tn * 16 + (lane & 15);
            if (MODE == 0 && c >= Nreal) continue;
            const float bvv = bias[c];
#pragma unroll
            for (int r = 0; r < 4; ++r) {
                float v = acc[tm][tn][r] + bvv;
                if (MODE == 1) v = (v >= 0.f) ? v : 0.2f * v;
                const size_t o = (size_t)(r0 + r) * ldc + c;
                if (MODE == 0)
                    ((float*)Cout)[o] = v;
                else
                    ((u16*)Cout)[o] = f2b(v);
            }
        }
    }
}

// ---------------- VQ: fp32 argmin + fp32 gather + fp32 loss; one wave per row ----------------
__global__ __launch_bounds__(256) void vq_kernel(
    const float* __restrict__ D, const float* __restrict__ enorm,
    const float* __restrict__ embF, const f16* __restrict__ zh, const f16* __restrict__ zl,
    u16* __restrict__ qb, float* __restrict__ lossSum) {
    const int lane = threadIdx.x & 63;
    const int row = blockIdx.x * 4 + (threadIdx.x >> 6);
    const float* d = D + (size_t)row * NUM_EMB;
    float best = 3.4e38f;
    int bidx = NUM_EMB;
    for (int j = 0; j < NUM_EMB / 64; ++j) {
        int col = j * 64 + lane;
        float v = enorm[col] - 2.0f * d[col];
        if (v < best || (v == best && col < bidx)) { best = v; bidx = col; }
    }
    for (int off = 32; off > 0; off >>= 1) {
        float ov = __shfl_down(best, off);
        int oi = __shfl_down(bidx, off);
        if (ov < best || (ov == best && oi < bidx)) { best = ov; bidx = oi; }
    }
    bidx = __shfl(bidx, 0);
    // gather fp32 codebook row (lane covers 8 floats), bf16-ify for decoder, fp32 loss
    const float4 q0 = ((const float4*)(embF + (size_t)bidx * LATENT))[2 * lane];
    const float4 q1 = ((const float4*)(embF + (size_t)bidx * LATENT))[2 * lane + 1];
    float qf[8] = {q0.x, q0.y, q0.z, q0.w, q1.x, q1.y, q1.z, q1.w};
    u16 qpack[8];
#pragma unroll
    for (int t = 0; t < 8; ++t) qpack[t] = f2b(qf[t]);
    *(uint4*)(qb + (size_t)row * LATENT + lane * 8) = *(const uint4*)qpack;

    v8hf zh8 = *(const v8hf*)(zh + (size_t)row * LATENT + lane * 8);
    v8hf zl8 = *(const v8hf*)(zl + (size_t)row * LATENT + lane * 8);
    float s = 0.f;
#pragma unroll
    for (int t = 0; t < 8; ++t) {
        float z = ((float)zh8[t] + (float)zl8[t] * INV_LO) * (1.0f / SA);
        float df = qf[t] - z;
        s += df * df;
    }
    for (int off = 32; off > 0; off >>= 1) s += __shfl_down(s, off);
    if (lane == 0) atomicAdd(lossSum, s);
}

__global__ void finalize(const float* __restrict__ lossSum, float* __restrict__ outLoss) {
    outLoss[0] = 1.25f * lossSum[0] / (float)(BATCH * LATENT);
}

// ---------------- launch ----------------
extern "C" void kernel_launch(void* const* d_in, const int* in_sizes, int n_in,
                              void* d_out, int out_size, void* d_ws, size_t ws_size,
                              hipStream_t stream) {
    const float* x = (const float*)d_in[0];
    const float* W1 = (const float*)d_in[1];
    const float* b1 = (const float*)d_in[2];
    const float* W2 = (const float*)d_in[3];
    const float* b2 = (const float*)d_in[4];
    const float* emb = (const float*)d_in[5];
    const float* W3 = (const float*)d_in[6];
    const float* b3 = (const float*)d_in[7];
    const float* W4 = (const float*)d_in[8];
    const float* b4 = (const float*)d_in[9];
    float* out = (float*)d_out;

    char* ws = (char*)d_ws;
    size_t off = 0;
    auto alloc = [&](size_t bytes) {
        void* p = ws + off;
        off += (bytes + 255) & ~(size_t)255;
        return p;
    };
    // A: h_hi (f16 16384x2048) -> D (f32 16384x1024), both 67.1MB
    char* A = (char*)alloc((size_t)BATCH * H_ENC * 2);
    // B: h_lo (f16) -> h2 (bf16 16384x2048)
    char* Breg = (char*)alloc((size_t)BATCH * H_ENC * 2);
    // C: xh+xl (f16 16384x704 each) -> zh+zl (f16 16384x512 each)
    char* C = (char*)alloc((size_t)BATCH * IN_PAD * 2 * 2);
    u16* qb = (u16*)alloc((size_t)BATCH * LATENT * 2);
    f16* W1Th = (f16*)alloc((size_t)H_ENC * IN_PAD * 2);
    f16* W1Tl = (f16*)alloc((size_t)H_ENC * IN_PAD * 2);
    f16* W2Th = (f16*)alloc((size_t)LATENT * H_ENC * 2);
    f16* W2Tl = (f16*)alloc((size_t)LATENT * H_ENC * 2);
    f16* eTh = (f16*)alloc((size_t)NUM_EMB * LATENT * 2);
    f16* eTl = (f16*)alloc((size_t)NUM_EMB * LATENT * 2);
    float* eTf = (float*)alloc((size_t)NUM_EMB * LATENT * 4);
    u16* W3T = (u16*)alloc((size_t)H_DEC * LATENT * 2);
    u16* W4T = (u16*)alloc((size_t)OUT_PAD * H_DEC * 2);
    float* enorm = (float*)alloc(NUM_EMB * 4);
    float* lossSum = (float*)alloc(256);

    f16* h_hi = (f16*)A;
    f16* h_lo = (f16*)Breg;
    float* D = (float*)A;
    u16* h2 = (u16*)Breg;
    f16* xh = (f16*)C;
    f16* xl = xh + (size_t)BATCH * IN_PAD;
    f16* zh = (f16*)C;
    f16* zl = zh + (size_t)BATCH * LATENT;

    // conversions
    split_x<<<(BATCH * IN_PAD + 255) / 256, 256, 0, stream>>>(x, xh, xl);
    transpose_split<<<dim3(IN_PAD / 32, H_ENC / 32), dim3(32, 8), 0, stream>>>(W1, W1Th, W1Tl, nullptr, IN_DIM, H_ENC, IN_PAD, SB);
    transpose_split<<<dim3(H_ENC / 32, LATENT / 32), dim3(32, 8), 0, stream>>>(W2, W2Th, W2Tl, nullptr, H_ENC, LATENT, H_ENC, SB);
    transpose_split<<<dim3(LATENT / 32, NUM_EMB / 32), dim3(32, 8), 0, stream>>>(emb, eTh, eTl, eTf, LATENT, NUM_EMB, LATENT, SB);
    transpose_pad<<<dim3(LATENT / 32, H_DEC / 32), dim3(32, 8), 0, stream>>>(W3, W3T, LATENT, H_DEC, LATENT, H_DEC);
    transpose_pad<<<dim3(H_DEC / 32, OUT_PAD / 32), dim3(32, 8), 0, stream>>>(W4, W4T, H_DEC, OUT_DIM, H_DEC, OUT_PAD);
    enorm_k<<<(NUM_EMB + 255) / 256, 256, 0, stream>>>(emb, enorm);
    zero_loss<<<1, 64, 0, stream>>>(lossSum);

    // precise encoder + distance path (fp16x2, 3 MFMA passes)
    gemm2<1><<<dim3(H_ENC / 128, BATCH / 128), 256, 0, stream>>>(xh, xl, W1Th, W1Tl, b1, h_hi, h_lo, nullptr, H_ENC, IN_PAD);
    gemm2<2><<<dim3(LATENT / 128, BATCH / 128), 256, 0, stream>>>(h_hi, h_lo, W2Th, W2Tl, b2, zh, zl, nullptr, LATENT, H_ENC);
    gemm2<3><<<dim3(NUM_EMB / 128, BATCH / 128), 256, 0, stream>>>(zh, zl, eTh, eTl, nullptr, nullptr, nullptr, D, NUM_EMB, LATENT);
    // VQ
    vq_kernel<<<BATCH / 4, 256, 0, stream>>>(D, enorm, eTf, zh, zl, qb, lossSum);
    // decoder (bf16)
    gemm_bt<1><<<dim3(H_DEC / 128, BATCH / 128), 256, 0, stream>>>(qb, W3T, b3, h2, H_DEC, LATENT, H_DEC, H_DEC);
    gemm_bt<0><<<dim3(OUT_PAD / 128, BATCH / 128), 256, 0, stream>>>(h2, W4T, b4, out, OUT_PAD, H_DEC, OUT_DIM, OUT_DIM);
    finalize<<<1, 1, 0, stream>>>(lossSum, out + (size_t)BATCH * OUT_DIM);

    (void)in_sizes; (void)n_in; (void)out_size; (void)ws_size;
}

// Round 3
// 847.217 us; speedup vs baseline: 1.3470x; 1.3470x over previous
//
#include <hip/hip_runtime.h>

typedef unsigned short u16;
typedef unsigned int u32;
typedef __bf16 v8bf __attribute__((ext_vector_type(8)));
typedef _Float16 f16;
typedef _Float16 v8hf __attribute__((ext_vector_type(8)));
typedef float f32x4 __attribute__((ext_vector_type(4)));

#define BATCH 16384
#define IN_DIM 700
#define IN_PAD 704
#define H_ENC 2048
#define LATENT 512
#define H_DEC 2048
#define OUT_DIM 700
#define OUT_PAD 768
#define NUM_EMB 1024

// pre-scales keep split-hi (and nearly all split-lo) in fp16 normal range
#define SA 16.0f
#define SB 64.0f
#define INV_SASB 9.765625e-4f   // 2^-10 exact

__device__ __forceinline__ float b2f(u16 u) {
    u32 x = ((u32)u) << 16;
    return __uint_as_float(x);
}
__device__ __forceinline__ u16 f2b(float f) {  // round-to-nearest-even
    u32 x = __float_as_uint(f);
    u32 r = x + 0x7fffu + ((x >> 16) & 1u);
    return (u16)(r >> 16);
}
// unscaled residual split: v = hi + lo (lo may be subnormal for tiny v — bounded error)
__device__ __forceinline__ void splitf(float v, f16& hi, f16& lo) {
    hi = (f16)v;
    lo = (f16)(v - (float)hi);
}

// async global->LDS, 16B per lane; lds dest wave-uniform base (+lane*16 by HW)
__device__ __forceinline__ void gld16(const void* g, void* s) {
    __builtin_amdgcn_global_load_lds((const __attribute__((address_space(1))) void*)g,
                                     (__attribute__((address_space(3))) void*)s, 16, 0, 0);
}

// ---------------- conversion kernels ----------------

__global__ void split_x(const float* __restrict__ x, f16* __restrict__ xh, f16* __restrict__ xl) {
    int idx = blockIdx.x * 256 + threadIdx.x;
    if (idx >= BATCH * IN_PAD) return;
    int r = idx / IN_PAD, c = idx - r * IN_PAD;
    float v = (c < IN_DIM) ? x[(size_t)r * IN_DIM + c] * SA : 0.f;
    f16 hi, lo;
    splitf(v, hi, lo);
    xh[idx] = hi;
    xl[idx] = lo;
}

// W:[K][N] fp32 row-major -> Th/Tl:[N][Kp] f16 split of W*scale (zero padded); Tf optional raw fp32
__global__ void transpose_split(const float* __restrict__ W, f16* __restrict__ Th,
                                f16* __restrict__ Tl, float* __restrict__ Tf,
                                int K, int N, int Kp, float scale) {
    __shared__ float tile[32][33];
    int kb = blockIdx.x * 32, nb = blockIdx.y * 32;
    int tx = threadIdx.x, ty = threadIdx.y;
    for (int i = ty; i < 32; i += 8) {
        int k = kb + i, n = nb + tx;
        tile[i][tx] = (k < K && n < N) ? W[(size_t)k * N + n] : 0.f;
    }
    __syncthreads();
    for (int i = ty; i < 32; i += 8) {
        int n = nb + i, kk = kb + tx;
        if (n < N && kk < Kp) {
            float v = tile[tx][i];
            if (Tf) Tf[(size_t)n * Kp + kk] = v;
            f16 hi, lo;
            splitf(v * scale, hi, lo);
            Th[(size_t)n * Kp + kk] = hi;
            Tl[(size_t)n * Kp + kk] = lo;
        }
    }
}

// W:[K][N] fp32 -> WT:[Np][Kp] bf16 (zero padded) — decoder weights
__global__ void transpose_pad(const float* __restrict__ W, u16* __restrict__ WT,
                              int K, int N, int Kp, int Np) {
    __shared__ float tile[32][33];
    int kb = blockIdx.x * 32, nb = blockIdx.y * 32;
    int tx = threadIdx.x, ty = threadIdx.y;
    for (int i = ty; i < 32; i += 8) {
        int k = kb + i, n = nb + tx;
        tile[i][tx] = (k < K && n < N) ? W[(size_t)k * N + n] : 0.f;
    }
    __syncthreads();
    for (int i = ty; i < 32; i += 8) {
        int n = nb + i, k = kb + tx;
        if (n < Np && k < Kp) WT[(size_t)n * Kp + k] = f2b(tile[tx][i]);
    }
}

__global__ void enorm_k(const float* __restrict__ emb, float* __restrict__ enorm) {
    int n = blockIdx.x * 256 + threadIdx.x;
    if (n >= NUM_EMB) return;
    double s = 0.0;  // exact-grade |e_j|^2
    for (int k = 0; k < LATENT; ++k) {
        float v = emb[(size_t)k * NUM_EMB + n];
        s += (double)v * (double)v;
    }
    enorm[n] = (float)s;
}

__global__ void zero_loss(float* p) {
    if (threadIdx.x == 0) p[0] = 0.f;
}

// ---------------- fp16x2 merged-accumulator GEMM: C = act((A*SA)@(B*SB)^T)/2^10 + bias ----------
// A = Ah + Al exactly (pre-scaled by SA); B = Bh + Bl (pre-scaled by SB), lo unscaled residuals.
// Single accumulator: per k-step  acc += Ah@Bl; acc += Al@Bh; acc += Ah@Bh  (big term last).
// MODE 1: leaky, store split(v*SA) to Oh/Ol      (h for next precise stage)
// MODE 2: store split(v*SA) to Oh/Ol             (z)
// MODE 3: raw f32 store to Of                    (distance dots)
template <int MODE>
__global__ __launch_bounds__(256) void gemm2(
    const f16* __restrict__ Ahg, const f16* __restrict__ Alg,
    const f16* __restrict__ Bhg, const f16* __restrict__ Blg,
    const float* __restrict__ bias,
    f16* __restrict__ Oh, f16* __restrict__ Ol, float* __restrict__ Of,
    int N, int K) {
    __shared__ f16 Ah[128 * 32];
    __shared__ f16 Al[128 * 32];
    __shared__ f16 Bh[128 * 32];
    __shared__ f16 Bl[128 * 32];
    const int w = threadIdx.x >> 6;
    const int lane = threadIdx.x & 63;
    const int bm = blockIdx.y * 128;
    const int bn = blockIdx.x * 128;

    const int srow = w * 32 + (lane >> 2);
    const int scol = (lane & 3) * 8;
    const f16* AhG = Ahg + (size_t)(bm + srow) * K + scol;
    const f16* AlG = Alg + (size_t)(bm + srow) * K + scol;
    const f16* BhG = Bhg + (size_t)(bn + srow) * K + scol;
    const f16* BlG = Blg + (size_t)(bn + srow) * K + scol;
    f16* AhW = &Ah[(w * 32) * 32];
    f16* AlW = &Al[(w * 32) * 32];
    f16* BhW = &Bh[(w * 32) * 32];
    f16* BlW = &Bl[(w * 32) * 32];

    const int mBase = (w >> 1) * 64;
    const int nBase = (w & 1) * 64;

    f32x4 acc[4][4];
    const f32x4 z4 = {0.f, 0.f, 0.f, 0.f};
#pragma unroll
    for (int a = 0; a < 4; ++a)
#pragma unroll
        for (int b = 0; b < 4; ++b) acc[a][b] = z4;

    for (int k0 = 0; k0 < K; k0 += 32) {
        gld16(AhG + k0, AhW);
        gld16(AhG + k0 + (size_t)16 * K, AhW + 16 * 32);
        gld16(AlG + k0, AlW);
        gld16(AlG + k0 + (size_t)16 * K, AlW + 16 * 32);
        gld16(BhG + k0, BhW);
        gld16(BhG + k0 + (size_t)16 * K, BhW + 16 * 32);
        gld16(BlG + k0, BlW);
        gld16(BlG + k0 + (size_t)16 * K, BlW + 16 * 32);
        __syncthreads();
        v8hf ah[4], al[4], bh[4], bl[4];
#pragma unroll
        for (int t = 0; t < 4; ++t) {
            const int ro = (t * 16 + (lane & 15)) * 32 + (lane >> 4) * 8;
            ah[t] = *(const v8hf*)&Ah[(mBase)*32 + ro];
            al[t] = *(const v8hf*)&Al[(mBase)*32 + ro];
            bh[t] = *(const v8hf*)&Bh[(nBase)*32 + ro];
            bl[t] = *(const v8hf*)&Bl[(nBase)*32 + ro];
        }
        // cross terms first (small), big hh term last — preserves their low bits
#pragma unroll
        for (int tm = 0; tm < 4; ++tm)
#pragma unroll
            for (int tn = 0; tn < 4; ++tn)
                acc[tm][tn] = __builtin_amdgcn_mfma_f32_16x16x32_f16(ah[tm], bl[tn], acc[tm][tn], 0, 0, 0);
#pragma unroll
        for (int tm = 0; tm < 4; ++tm)
#pragma unroll
            for (int tn = 0; tn < 4; ++tn)
                acc[tm][tn] = __builtin_amdgcn_mfma_f32_16x16x32_f16(al[tm], bh[tn], acc[tm][tn], 0, 0, 0);
#pragma unroll
        for (int tm = 0; tm < 4; ++tm)
#pragma unroll
            for (int tn = 0; tn < 4; ++tn)
                acc[tm][tn] = __builtin_amdgcn_mfma_f32_16x16x32_f16(ah[tm], bh[tn], acc[tm][tn], 0, 0, 0);
        __syncthreads();
    }

    // C/D frag layout col=lane&15, row=(lane>>4)*4+r
#pragma unroll
    for (int tm = 0; tm < 4; ++tm) {
        const int r0 = bm + mBase + tm * 16 + (lane >> 4) * 4;
#pragma unroll
        for (int tn = 0; tn < 4; ++tn) {
            const int c = bn + nBase + tn * 16 + (lane & 15);
            const float bvv = (MODE == 3) ? 0.f : bias[c];
#pragma unroll
            for (int r = 0; r < 4; ++r) {
                float v = acc[tm][tn][r] * INV_SASB + bvv;
                if (MODE == 1) v = (v >= 0.f) ? v : 0.2f * v;
                const size_t o = (size_t)(r0 + r) * N + c;
                if (MODE == 3) {
                    Of[o] = v;
                } else {
                    f16 hi, lo;
                    splitf(v * SA, hi, lo);
                    Oh[o] = hi;
                    Ol[o] = lo;
                }
            }
        }
    }
}

// ---------------- bf16 GEMM (decoder), C = act(A @ B^T + bias) ----------------
// MODE 0: f32 store, +bias, predicated c<Nreal (recon). MODE 1: bf16 store, +bias, leaky.
template <int MODE>
__global__ __launch_bounds__(256) void gemm_bt(
    const u16* __restrict__ A, const u16* __restrict__ B,
    const float* __restrict__ bias, void* __restrict__ Cout,
    int N, int K, int ldc, int Nreal) {
    __shared__ u16 As[128 * 32];
    __shared__ u16 Bs[128 * 32];
    const int w = threadIdx.x >> 6;
    const int lane = threadIdx.x & 63;
    const int bm = blockIdx.y * 128;
    const int bn = blockIdx.x * 128;

    const int srow = w * 32 + (lane >> 2);
    const int scol = (lane & 3) * 8;
    const u16* Ag = A + (size_t)(bm + srow) * K + scol;
    const u16* Bg = B + (size_t)(bn + srow) * K + scol;
    u16* AsW = &As[(w * 32) * 32];
    u16* BsW = &Bs[(w * 32) * 32];

    const int mBase = (w >> 1) * 64;
    const int nBase = (w & 1) * 64;

    f32x4 acc[4][4];
    const f32x4 z4 = {0.f, 0.f, 0.f, 0.f};
#pragma unroll
    for (int a = 0; a < 4; ++a)
#pragma unroll
        for (int b = 0; b < 4; ++b) acc[a][b] = z4;

    for (int k0 = 0; k0 < K; k0 += 32) {
        gld16(Ag + k0, AsW);
        gld16(Ag + k0 + (size_t)16 * K, AsW + 16 * 32);
        gld16(Bg + k0, BsW);
        gld16(Bg + k0 + (size_t)16 * K, BsW + 16 * 32);
        __syncthreads();
        v8bf af[4], bv[4];
#pragma unroll
        for (int t = 0; t < 4; ++t) {
            af[t] = *(const v8bf*)&As[(mBase + t * 16 + (lane & 15)) * 32 + (lane >> 4) * 8];
            bv[t] = *(const v8bf*)&Bs[(nBase + t * 16 + (lane & 15)) * 32 + (lane >> 4) * 8];
        }
#pragma unroll
        for (int tm = 0; tm < 4; ++tm)
#pragma unroll
            for (int tn = 0; tn < 4; ++tn)
                acc[tm][tn] = __builtin_amdgcn_mfma_f32_16x16x32_bf16(af[tm], bv[tn], acc[tm][tn], 0, 0, 0);
        __syncthreads();
    }

#pragma unroll
    for (int tm = 0; tm < 4; ++tm) {
        const int r0 = bm + mBase + tm * 16 + (lane >> 4) * 4;
#pragma unroll
        for (int tn = 0; tn < 4; ++tn) {
            const int c = bn + nBase + tn * 16 + (lane & 15);
            if (MODE == 0 && c >= Nreal) continue;
            const float bvv = bias[c];
#pragma unroll
            for (int r = 0; r < 4; ++r) {
                float v = acc[tm][tn][r] + bvv;
                if (MODE == 1) v = (v >= 0.f) ? v : 0.2f * v;
                const size_t o = (size_t)(r0 + r) * ldc + c;
                if (MODE == 0)
                    ((float*)Cout)[o] = v;
                else
                    ((u16*)Cout)[o] = f2b(v);
            }
        }
    }
}

// ---------------- VQ: fp32 argmin + fp32 gather + fp32 loss; one wave per row ----------------
__global__ __launch_bounds__(256) void vq_kernel(
    const float* __restrict__ D, const float* __restrict__ enorm,
    const float* __restrict__ embF, const f16* __restrict__ zh, const f16* __restrict__ zl,
    u16* __restrict__ qb, float* __restrict__ lossSum) {
    const int lane = threadIdx.x & 63;
    const int row = blockIdx.x * 4 + (threadIdx.x >> 6);
    const float* d = D + (size_t)row * NUM_EMB;
    float best = 3.4e38f;
    int bidx = NUM_EMB;
    for (int j = 0; j < NUM_EMB / 64; ++j) {
        int col = j * 64 + lane;
        float v = enorm[col] - 2.0f * d[col];
        if (v < best || (v == best && col < bidx)) { best = v; bidx = col; }
    }
    for (int off = 32; off > 0; off >>= 1) {
        float ov = __shfl_down(best, off);
        int oi = __shfl_down(bidx, off);
        if (ov < best || (ov == best && oi < bidx)) { best = ov; bidx = oi; }
    }
    bidx = __shfl(bidx, 0);
    // gather fp32 codebook row (lane covers 8 floats), bf16-ify for decoder, fp32 loss
    const float4 q0 = ((const float4*)(embF + (size_t)bidx * LATENT))[2 * lane];
    const float4 q1 = ((const float4*)(embF + (size_t)bidx * LATENT))[2 * lane + 1];
    float qf[8] = {q0.x, q0.y, q0.z, q0.w, q1.x, q1.y, q1.z, q1.w};
    u16 qpack[8];
#pragma unroll
    for (int t = 0; t < 8; ++t) qpack[t] = f2b(qf[t]);
    *(uint4*)(qb + (size_t)row * LATENT + lane * 8) = *(const uint4*)qpack;

    v8hf zh8 = *(const v8hf*)(zh + (size_t)row * LATENT + lane * 8);
    v8hf zl8 = *(const v8hf*)(zl + (size_t)row * LATENT + lane * 8);
    float s = 0.f;
#pragma unroll
    for (int t = 0; t < 8; ++t) {
        float z = ((float)zh8[t] + (float)zl8[t]) * (1.0f / SA);
        float df = qf[t] - z;
        s += df * df;
    }
    for (int off = 32; off > 0; off >>= 1) s += __shfl_down(s, off);
    if (lane == 0) atomicAdd(lossSum, s);
}

__global__ void finalize(const float* __restrict__ lossSum, float* __restrict__ outLoss) {
    outLoss[0] = 1.25f * lossSum[0] / (float)(BATCH * LATENT);
}

// ---------------- launch ----------------
extern "C" void kernel_launch(void* const* d_in, const int* in_sizes, int n_in,
                              void* d_out, int out_size, void* d_ws, size_t ws_size,
                              hipStream_t stream) {
    const float* x = (const float*)d_in[0];
    const float* W1 = (const float*)d_in[1];
    const float* b1 = (const float*)d_in[2];
    const float* W2 = (const float*)d_in[3];
    const float* b2 = (const float*)d_in[4];
    const float* emb = (const float*)d_in[5];
    const float* W3 = (const float*)d_in[6];
    const float* b3 = (const float*)d_in[7];
    const float* W4 = (const float*)d_in[8];
    const float* b4 = (const float*)d_in[9];
    float* out = (float*)d_out;

    char* ws = (char*)d_ws;
    size_t off = 0;
    auto alloc = [&](size_t bytes) {
        void* p = ws + off;
        off += (bytes + 255) & ~(size_t)255;
        return p;
    };
    // A: h_hi (f16 16384x2048) -> D (f32 16384x1024), both 67.1MB
    char* A = (char*)alloc((size_t)BATCH * H_ENC * 2);
    // B: h_lo (f16) -> h2 (bf16 16384x2048)
    char* Breg = (char*)alloc((size_t)BATCH * H_ENC * 2);
    // C: xh+xl (f16 16384x704 each) -> zh+zl (f16 16384x512 each)
    char* C = (char*)alloc((size_t)BATCH * IN_PAD * 2 * 2);
    u16* qb = (u16*)alloc((size_t)BATCH * LATENT * 2);
    f16* W1Th = (f16*)alloc((size_t)H_ENC * IN_PAD * 2);
    f16* W1Tl = (f16*)alloc((size_t)H_ENC * IN_PAD * 2);
    f16* W2Th = (f16*)alloc((size_t)LATENT * H_ENC * 2);
    f16* W2Tl = (f16*)alloc((size_t)LATENT * H_ENC * 2);
    f16* eTh = (f16*)alloc((size_t)NUM_EMB * LATENT * 2);
    f16* eTl = (f16*)alloc((size_t)NUM_EMB * LATENT * 2);
    float* eTf = (float*)alloc((size_t)NUM_EMB * LATENT * 4);
    u16* W3T = (u16*)alloc((size_t)H_DEC * LATENT * 2);
    u16* W4T = (u16*)alloc((size_t)OUT_PAD * H_DEC * 2);
    float* enorm = (float*)alloc(NUM_EMB * 4);
    float* lossSum = (float*)alloc(256);

    f16* h_hi = (f16*)A;
    f16* h_lo = (f16*)Breg;
    float* D = (float*)A;
    u16* h2 = (u16*)Breg;
    f16* xh = (f16*)C;
    f16* xl = xh + (size_t)BATCH * IN_PAD;
    f16* zh = (f16*)C;
    f16* zl = zh + (size_t)BATCH * LATENT;

    // conversions
    split_x<<<(BATCH * IN_PAD + 255) / 256, 256, 0, stream>>>(x, xh, xl);
    transpose_split<<<dim3(IN_PAD / 32, H_ENC / 32), dim3(32, 8), 0, stream>>>(W1, W1Th, W1Tl, nullptr, IN_DIM, H_ENC, IN_PAD, SB);
    transpose_split<<<dim3(H_ENC / 32, LATENT / 32), dim3(32, 8), 0, stream>>>(W2, W2Th, W2Tl, nullptr, H_ENC, LATENT, H_ENC, SB);
    transpose_split<<<dim3(LATENT / 32, NUM_EMB / 32), dim3(32, 8), 0, stream>>>(emb, eTh, eTl, eTf, LATENT, NUM_EMB, LATENT, SB);
    transpose_pad<<<dim3(LATENT / 32, H_DEC / 32), dim3(32, 8), 0, stream>>>(W3, W3T, LATENT, H_DEC, LATENT, H_DEC);
    transpose_pad<<<dim3(H_DEC / 32, OUT_PAD / 32), dim3(32, 8), 0, stream>>>(W4, W4T, H_DEC, OUT_DIM, H_DEC, OUT_PAD);
    enorm_k<<<(NUM_EMB + 255) / 256, 256, 0, stream>>>(emb, enorm);
    zero_loss<<<1, 64, 0, stream>>>(lossSum);

    // precise encoder + distance path (fp16x2, merged accumulator, 3 MFMA passes)
    gemm2<1><<<dim3(H_ENC / 128, BATCH / 128), 256, 0, stream>>>(xh, xl, W1Th, W1Tl, b1, h_hi, h_lo, nullptr, H_ENC, IN_PAD);
    gemm2<2><<<dim3(LATENT / 128, BATCH / 128), 256, 0, stream>>>(h_hi, h_lo, W2Th, W2Tl, b2, zh, zl, nullptr, LATENT, H_ENC);
    gemm2<3><<<dim3(NUM_EMB / 128, BATCH / 128), 256, 0, stream>>>(zh, zl, eTh, eTl, nullptr, nullptr, nullptr, D, NUM_EMB, LATENT);
    // VQ
    vq_kernel<<<BATCH / 4, 256, 0, stream>>>(D, enorm, eTf, zh, zl, qb, lossSum);
    // decoder (bf16)
    gemm_bt<1><<<dim3(H_DEC / 128, BATCH / 128), 256, 0, stream>>>(qb, W3T, b3, h2, H_DEC, LATENT, H_DEC, H_DEC);
    gemm_bt<0><<<dim3(OUT_PAD / 128, BATCH / 128), 256, 0, stream>>>(h2, W4T, b4, out, OUT_PAD, H_DEC, OUT_DIM, OUT_DIM);
    finalize<<<1, 1, 0, stream>>>(lossSum, out + (size_t)BATCH * OUT_DIM);

    (void)in_sizes; (void)n_in; (void)out_size; (void)ws_size;
}

// Round 5
// 647.964 us; speedup vs baseline: 1.7612x; 1.3075x over previous
//
#include <hip/hip_runtime.h>

typedef unsigned short u16;
typedef unsigned int u32;
typedef unsigned long long u64;
typedef __bf16 v8bf __attribute__((ext_vector_type(8)));
typedef _Float16 f16;
typedef _Float16 v8hf __attribute__((ext_vector_type(8)));
typedef float f32x4 __attribute__((ext_vector_type(4)));

#define BATCH 16384
#define IN_DIM 700
#define IN_PAD 704
#define H_ENC 2048
#define LATENT 512
#define H_DEC 2048
#define OUT_DIM 700
#define OUT_PAD 768
#define NUM_EMB 1024

// pre-scales keep split-hi (and nearly all split-lo) in fp16 normal range
#define SA 16.0f
#define SB 64.0f
#define INV_SASB 9.765625e-4f   // 2^-10 exact

__device__ __forceinline__ float b2f(u16 u) {
    u32 x = ((u32)u) << 16;
    return __uint_as_float(x);
}
__device__ __forceinline__ u16 f2b(float f) {  // round-to-nearest-even
    u32 x = __float_as_uint(f);
    u32 r = x + 0x7fffu + ((x >> 16) & 1u);
    return (u16)(r >> 16);
}
// unscaled residual split: v = hi + lo
__device__ __forceinline__ void splitf(float v, f16& hi, f16& lo) {
    hi = (f16)v;
    lo = (f16)(v - (float)hi);
}
// float -> monotone-orderable u32 (ascending)
__device__ __forceinline__ u32 f2ord(float f) {
    u32 u = __float_as_uint(f);
    return (u >> 31) ? ~u : (u | 0x80000000u);
}

// async global->LDS, 16B per lane; lds dest wave-uniform base (+lane*16 by HW)
__device__ __forceinline__ void gld16(const void* g, void* s) {
    __builtin_amdgcn_global_load_lds((const __attribute__((address_space(1))) void*)g,
                                     (__attribute__((address_space(3))) void*)s, 16, 0, 0);
}

// ---------------- conversion kernels ----------------

__global__ void split_x(const float* __restrict__ x, f16* __restrict__ xh, f16* __restrict__ xl) {
    int idx = blockIdx.x * 256 + threadIdx.x;
    if (idx >= BATCH * IN_PAD) return;
    int r = idx / IN_PAD, c = idx - r * IN_PAD;
    float v = (c < IN_DIM) ? x[(size_t)r * IN_DIM + c] * SA : 0.f;
    f16 hi, lo;
    splitf(v, hi, lo);
    xh[idx] = hi;
    xl[idx] = lo;
}

// W:[K][N] fp32 row-major -> Th/Tl:[N][Kp] f16 split of W*scale (zero padded); Tf optional raw fp32
__global__ void transpose_split(const float* __restrict__ W, f16* __restrict__ Th,
                                f16* __restrict__ Tl, float* __restrict__ Tf,
                                int K, int N, int Kp, float scale) {
    __shared__ float tile[32][33];
    int kb = blockIdx.x * 32, nb = blockIdx.y * 32;
    int tx = threadIdx.x, ty = threadIdx.y;
    for (int i = ty; i < 32; i += 8) {
        int k = kb + i, n = nb + tx;
        tile[i][tx] = (k < K && n < N) ? W[(size_t)k * N + n] : 0.f;
    }
    __syncthreads();
    for (int i = ty; i < 32; i += 8) {
        int n = nb + i, kk = kb + tx;
        if (n < N && kk < Kp) {
            float v = tile[tx][i];
            if (Tf) Tf[(size_t)n * Kp + kk] = v;
            f16 hi, lo;
            splitf(v * scale, hi, lo);
            Th[(size_t)n * Kp + kk] = hi;
            Tl[(size_t)n * Kp + kk] = lo;
        }
    }
}

// W:[K][N] fp32 -> WT:[Np][Kp] bf16 (zero padded) — decoder weights
__global__ void transpose_pad(const float* __restrict__ W, u16* __restrict__ WT,
                              int K, int N, int Kp, int Np) {
    __shared__ float tile[32][33];
    int kb = blockIdx.x * 32, nb = blockIdx.y * 32;
    int tx = threadIdx.x, ty = threadIdx.y;
    for (int i = ty; i < 32; i += 8) {
        int k = kb + i, n = nb + tx;
        tile[i][tx] = (k < K && n < N) ? W[(size_t)k * N + n] : 0.f;
    }
    __syncthreads();
    for (int i = ty; i < 32; i += 8) {
        int n = nb + i, k = kb + tx;
        if (n < Np && k < Kp) WT[(size_t)n * Kp + k] = f2b(tile[tx][i]);
    }
}

__global__ void enorm_k(const float* __restrict__ emb, float* __restrict__ enorm) {
    int n = blockIdx.x * 256 + threadIdx.x;
    if (n >= NUM_EMB) return;
    double s = 0.0;  // exact-grade |e_j|^2
    for (int k = 0; k < LATENT; ++k) {
        float v = emb[(size_t)k * NUM_EMB + n];
        s += (double)v * (double)v;
    }
    enorm[n] = (float)s;
}

// ---------------- fp16x2 merged-accumulator GEMM: C = act((A*SA)@(B*SB)^T)/2^10 + bias ----------
// MODE 1: leaky, store split(v*SA) to Oh/Ol      (h)
// MODE 2: store split(v*SA) to Oh/Ol             (z)
// MODE 3: VQ distance pass — no D store; per-row partial argmin. Each wave covers a 64x64
//         quadrant (2 waves share rows!), so each wave writes its OWN slot:
//         Part[row*16 + blockIdx.x*2 + (w&1)]. bias = enorm.
template <int MODE>
__global__ __launch_bounds__(256) void gemm2(
    const f16* __restrict__ Ahg, const f16* __restrict__ Alg,
    const f16* __restrict__ Bhg, const f16* __restrict__ Blg,
    const float* __restrict__ bias,
    f16* __restrict__ Oh, f16* __restrict__ Ol, u64* __restrict__ Part,
    int N, int K) {
    __shared__ f16 Ah[128 * 32];
    __shared__ f16 Al[128 * 32];
    __shared__ f16 Bh[128 * 32];
    __shared__ f16 Bl[128 * 32];
    const int w = threadIdx.x >> 6;
    const int lane = threadIdx.x & 63;
    const int bm = blockIdx.y * 128;
    const int bn = blockIdx.x * 128;

    const int srow = w * 32 + (lane >> 2);
    const int scol = (lane & 3) * 8;
    const f16* AhG = Ahg + (size_t)(bm + srow) * K + scol;
    const f16* AlG = Alg + (size_t)(bm + srow) * K + scol;
    const f16* BhG = Bhg + (size_t)(bn + srow) * K + scol;
    const f16* BlG = Blg + (size_t)(bn + srow) * K + scol;
    f16* AhW = &Ah[(w * 32) * 32];
    f16* AlW = &Al[(w * 32) * 32];
    f16* BhW = &Bh[(w * 32) * 32];
    f16* BlW = &Bl[(w * 32) * 32];

    const int mBase = (w >> 1) * 64;
    const int nBase = (w & 1) * 64;

    f32x4 acc[4][4];
    const f32x4 z4 = {0.f, 0.f, 0.f, 0.f};
#pragma unroll
    for (int a = 0; a < 4; ++a)
#pragma unroll
        for (int b = 0; b < 4; ++b) acc[a][b] = z4;

    for (int k0 = 0; k0 < K; k0 += 32) {
        gld16(AhG + k0, AhW);
        gld16(AhG + k0 + (size_t)16 * K, AhW + 16 * 32);
        gld16(AlG + k0, AlW);
        gld16(AlG + k0 + (size_t)16 * K, AlW + 16 * 32);
        gld16(BhG + k0, BhW);
        gld16(BhG + k0 + (size_t)16 * K, BhW + 16 * 32);
        gld16(BlG + k0, BlW);
        gld16(BlG + k0 + (size_t)16 * K, BlW + 16 * 32);
        __syncthreads();
        v8hf ah[4], al[4], bh[4], bl[4];
#pragma unroll
        for (int t = 0; t < 4; ++t) {
            const int ro = (t * 16 + (lane & 15)) * 32 + (lane >> 4) * 8;
            ah[t] = *(const v8hf*)&Ah[(mBase)*32 + ro];
            al[t] = *(const v8hf*)&Al[(mBase)*32 + ro];
            bh[t] = *(const v8hf*)&Bh[(nBase)*32 + ro];
            bl[t] = *(const v8hf*)&Bl[(nBase)*32 + ro];
        }
        // cross terms first (small), big hh term last — preserves their low bits
#pragma unroll
        for (int tm = 0; tm < 4; ++tm)
#pragma unroll
            for (int tn = 0; tn < 4; ++tn)
                acc[tm][tn] = __builtin_amdgcn_mfma_f32_16x16x32_f16(ah[tm], bl[tn], acc[tm][tn], 0, 0, 0);
#pragma unroll
        for (int tm = 0; tm < 4; ++tm)
#pragma unroll
            for (int tn = 0; tn < 4; ++tn)
                acc[tm][tn] = __builtin_amdgcn_mfma_f32_16x16x32_f16(al[tm], bh[tn], acc[tm][tn], 0, 0, 0);
#pragma unroll
        for (int tm = 0; tm < 4; ++tm)
#pragma unroll
            for (int tn = 0; tn < 4; ++tn)
                acc[tm][tn] = __builtin_amdgcn_mfma_f32_16x16x32_f16(ah[tm], bh[tn], acc[tm][tn], 0, 0, 0);
        __syncthreads();
    }

    if (MODE == 3) {
        // per-row partial argmin over this wave's 64 cols.
        // C layout: row = mBase+tm*16+(lane>>4)*4+r, col = nBase+tn*16+(lane&15)
#pragma unroll
        for (int tm = 0; tm < 4; ++tm) {
#pragma unroll
            for (int r = 0; r < 4; ++r) {
                u64 key = ~0ull;
#pragma unroll
                for (int tn = 0; tn < 4; ++tn) {
                    const int c = bn + nBase + tn * 16 + (lane & 15);
                    float score = bias[c] - 2.0f * (acc[tm][tn][r] * INV_SASB);
                    u64 k = ((u64)f2ord(score) << 10) | (u32)c;
                    key = (k < key) ? k : key;
                }
                // reduce across the 16 lanes holding this C-row (xor within low 4 bits)
#pragma unroll
                for (int m = 1; m < 16; m <<= 1) {
                    u64 o = __shfl_xor((unsigned long long)key, m);
                    key = (o < key) ? o : key;
                }
                if ((lane & 15) == 0) {
                    const int row = bm + mBase + tm * 16 + (lane >> 4) * 4 + r;
                    Part[(size_t)row * 16 + blockIdx.x * 2 + (w & 1)] = key;
                }
            }
        }
        return;
    }

    // C/D frag layout col=lane&15, row=(lane>>4)*4+r
#pragma unroll
    for (int tm = 0; tm < 4; ++tm) {
        const int r0 = bm + mBase + tm * 16 + (lane >> 4) * 4;
#pragma unroll
        for (int tn = 0; tn < 4; ++tn) {
            const int c = bn + nBase + tn * 16 + (lane & 15);
            const float bvv = bias[c];
#pragma unroll
            for (int r = 0; r < 4; ++r) {
                float v = acc[tm][tn][r] * INV_SASB + bvv;
                if (MODE == 1) v = (v >= 0.f) ? v : 0.2f * v;
                const size_t o = (size_t)(r0 + r) * N + c;
                f16 hi, lo;
                splitf(v * SA, hi, lo);
                Oh[o] = hi;
                Ol[o] = lo;
            }
        }
    }
}

// ---------------- bf16 GEMM (decoder), C = act(A @ B^T + bias) ----------------
// MODE 0: f32 store, +bias, predicated c<Nreal (recon). MODE 1: bf16 store, +bias, leaky.
template <int MODE>
__global__ __launch_bounds__(256) void gemm_bt(
    const u16* __restrict__ A, const u16* __restrict__ B,
    const float* __restrict__ bias, void* __restrict__ Cout,
    int N, int K, int ldc, int Nreal) {
    __shared__ u16 As[128 * 32];
    __shared__ u16 Bs[128 * 32];
    const int w = threadIdx.x >> 6;
    const int lane = threadIdx.x & 63;
    const int bm = blockIdx.y * 128;
    const int bn = blockIdx.x * 128;

    const int srow = w * 32 + (lane >> 2);
    const int scol = (lane & 3) * 8;
    const u16* Ag = A + (size_t)(bm + srow) * K + scol;
    const u16* Bg = B + (size_t)(bn + srow) * K + scol;
    u16* AsW = &As[(w * 32) * 32];
    u16* BsW = &Bs[(w * 32) * 32];

    const int mBase = (w >> 1) * 64;
    const int nBase = (w & 1) * 64;

    f32x4 acc[4][4];
    const f32x4 z4 = {0.f, 0.f, 0.f, 0.f};
#pragma unroll
    for (int a = 0; a < 4; ++a)
#pragma unroll
        for (int b = 0; b < 4; ++b) acc[a][b] = z4;

    for (int k0 = 0; k0 < K; k0 += 32) {
        gld16(Ag + k0, AsW);
        gld16(Ag + k0 + (size_t)16 * K, AsW + 16 * 32);
        gld16(Bg + k0, BsW);
        gld16(Bg + k0 + (size_t)16 * K, BsW + 16 * 32);
        __syncthreads();
        v8bf af[4], bv[4];
#pragma unroll
        for (int t = 0; t < 4; ++t) {
            af[t] = *(const v8bf*)&As[(mBase + t * 16 + (lane & 15)) * 32 + (lane >> 4) * 8];
            bv[t] = *(const v8bf*)&Bs[(nBase + t * 16 + (lane & 15)) * 32 + (lane >> 4) * 8];
        }
#pragma unroll
        for (int tm = 0; tm < 4; ++tm)
#pragma unroll
            for (int tn = 0; tn < 4; ++tn)
                acc[tm][tn] = __builtin_amdgcn_mfma_f32_16x16x32_bf16(af[tm], bv[tn], acc[tm][tn], 0, 0, 0);
        __syncthreads();
    }

#pragma unroll
    for (int tm = 0; tm < 4; ++tm) {
        const int r0 = bm + mBase + tm * 16 + (lane >> 4) * 4;
#pragma unroll
        for (int tn = 0; tn < 4; ++tn) {
            const int c = bn + nBase + tn * 16 + (lane & 15);
            if (MODE == 0 && c >= Nreal) continue;
            const float bvv = bias[c];
#pragma unroll
            for (int r = 0; r < 4; ++r) {
                float v = acc[tm][tn][r] + bvv;
                if (MODE == 1) v = (v >= 0.f) ? v : 0.2f * v;
                const size_t o = (size_t)(r0 + r) * ldc + c;
                if (MODE == 0)
                    ((float*)Cout)[o] = v;
                else
                    ((u16*)Cout)[o] = f2b(v);
            }
        }
    }
}

// ---------------- VQ finish: reduce 16 partials/row, gather, loss partials; wave per row --------
__global__ __launch_bounds__(256) void vq2(
    const u64* __restrict__ Part, const float* __restrict__ embF,
    const f16* __restrict__ zh, const f16* __restrict__ zl,
    u16* __restrict__ qb, float* __restrict__ lossPart) {
    __shared__ float ls[4];
    const int lane = threadIdx.x & 63;
    const int wv = threadIdx.x >> 6;
    const int row = blockIdx.x * 4 + wv;

    u64 key = (lane < 16) ? Part[(size_t)row * 16 + lane] : ~0ull;
#pragma unroll
    for (int m = 1; m < 16; m <<= 1) {
        u64 o = __shfl_xor((unsigned long long)key, m);
        key = (o < key) ? o : key;
    }
    const int bidx = (int)(__shfl((unsigned long long)key, 0) & 1023ull);

    // gather fp32 codebook row (lane covers 8 floats), bf16-ify for decoder, fp32 loss
    const float4 q0 = ((const float4*)(embF + (size_t)bidx * LATENT))[2 * lane];
    const float4 q1 = ((const float4*)(embF + (size_t)bidx * LATENT))[2 * lane + 1];
    float qf[8] = {q0.x, q0.y, q0.z, q0.w, q1.x, q1.y, q1.z, q1.w};
    u16 qpack[8];
#pragma unroll
    for (int t = 0; t < 8; ++t) qpack[t] = f2b(qf[t]);
    *(uint4*)(qb + (size_t)row * LATENT + lane * 8) = *(const uint4*)qpack;

    v8hf zh8 = *(const v8hf*)(zh + (size_t)row * LATENT + lane * 8);
    v8hf zl8 = *(const v8hf*)(zl + (size_t)row * LATENT + lane * 8);
    float s = 0.f;
#pragma unroll
    for (int t = 0; t < 8; ++t) {
        float z = ((float)zh8[t] + (float)zl8[t]) * (1.0f / SA);
        float df = qf[t] - z;
        s += df * df;
    }
    for (int off = 32; off > 0; off >>= 1) s += __shfl_down(s, off);
    if (lane == 0) ls[wv] = s;
    __syncthreads();
    if (threadIdx.x == 0) lossPart[blockIdx.x] = ls[0] + ls[1] + ls[2] + ls[3];
}

__global__ __launch_bounds__(256) void reduce_loss(const float* __restrict__ lossPart,
                                                   float* __restrict__ outLoss) {
    __shared__ float ls[4];
    const int lane = threadIdx.x & 63;
    const int wv = threadIdx.x >> 6;
    float s = 0.f;
    for (int i = threadIdx.x; i < BATCH / 4; i += 256) s += lossPart[i];
    for (int off = 32; off > 0; off >>= 1) s += __shfl_down(s, off);
    if (lane == 0) ls[wv] = s;
    __syncthreads();
    if (threadIdx.x == 0)
        outLoss[0] = 1.25f * (ls[0] + ls[1] + ls[2] + ls[3]) / (float)(BATCH * LATENT);
}

// ---------------- launch ----------------
extern "C" void kernel_launch(void* const* d_in, const int* in_sizes, int n_in,
                              void* d_out, int out_size, void* d_ws, size_t ws_size,
                              hipStream_t stream) {
    const float* x = (const float*)d_in[0];
    const float* W1 = (const float*)d_in[1];
    const float* b1 = (const float*)d_in[2];
    const float* W2 = (const float*)d_in[3];
    const float* b2 = (const float*)d_in[4];
    const float* emb = (const float*)d_in[5];
    const float* W3 = (const float*)d_in[6];
    const float* b3 = (const float*)d_in[7];
    const float* W4 = (const float*)d_in[8];
    const float* b4 = (const float*)d_in[9];
    float* out = (float*)d_out;

    char* ws = (char*)d_ws;
    size_t off = 0;
    auto alloc = [&](size_t bytes) {
        void* p = ws + off;
        off += (bytes + 255) & ~(size_t)255;
        return p;
    };
    // A: h_hi (f16 16384x2048)
    char* A = (char*)alloc((size_t)BATCH * H_ENC * 2);
    // B: h_lo (f16) -> h2 (bf16 16384x2048)
    char* Breg = (char*)alloc((size_t)BATCH * H_ENC * 2);
    // C: xh+xl (f16 16384x704 each) -> zh+zl (f16 16384x512 each)
    char* C = (char*)alloc((size_t)BATCH * IN_PAD * 2 * 2);
    u16* qb = (u16*)alloc((size_t)BATCH * LATENT * 2);
    u64* Part = (u64*)alloc((size_t)BATCH * 16 * 8);
    float* lossPart = (float*)alloc((BATCH / 4) * 4);
    f16* W1Th = (f16*)alloc((size_t)H_ENC * IN_PAD * 2);
    f16* W1Tl = (f16*)alloc((size_t)H_ENC * IN_PAD * 2);
    f16* W2Th = (f16*)alloc((size_t)LATENT * H_ENC * 2);
    f16* W2Tl = (f16*)alloc((size_t)LATENT * H_ENC * 2);
    f16* eTh = (f16*)alloc((size_t)NUM_EMB * LATENT * 2);
    f16* eTl = (f16*)alloc((size_t)NUM_EMB * LATENT * 2);
    float* eTf = (float*)alloc((size_t)NUM_EMB * LATENT * 4);
    u16* W3T = (u16*)alloc((size_t)H_DEC * LATENT * 2);
    u16* W4T = (u16*)alloc((size_t)OUT_PAD * H_DEC * 2);
    float* enorm = (float*)alloc(NUM_EMB * 4);

    f16* h_hi = (f16*)A;
    f16* h_lo = (f16*)Breg;
    u16* h2 = (u16*)Breg;
    f16* xh = (f16*)C;
    f16* xl = xh + (size_t)BATCH * IN_PAD;
    f16* zh = (f16*)C;
    f16* zl = zh + (size_t)BATCH * LATENT;

    // conversions
    split_x<<<(BATCH * IN_PAD + 255) / 256, 256, 0, stream>>>(x, xh, xl);
    transpose_split<<<dim3(IN_PAD / 32, H_ENC / 32), dim3(32, 8), 0, stream>>>(W1, W1Th, W1Tl, nullptr, IN_DIM, H_ENC, IN_PAD, SB);
    transpose_split<<<dim3(H_ENC / 32, LATENT / 32), dim3(32, 8), 0, stream>>>(W2, W2Th, W2Tl, nullptr, H_ENC, LATENT, H_ENC, SB);
    transpose_split<<<dim3(LATENT / 32, NUM_EMB / 32), dim3(32, 8), 0, stream>>>(emb, eTh, eTl, eTf, LATENT, NUM_EMB, LATENT, SB);
    transpose_pad<<<dim3(LATENT / 32, H_DEC / 32), dim3(32, 8), 0, stream>>>(W3, W3T, LATENT, H_DEC, LATENT, H_DEC);
    transpose_pad<<<dim3(H_DEC / 32, OUT_PAD / 32), dim3(32, 8), 0, stream>>>(W4, W4T, H_DEC, OUT_DIM, H_DEC, OUT_PAD);
    enorm_k<<<(NUM_EMB + 255) / 256, 256, 0, stream>>>(emb, enorm);

    // precise encoder + distance path (fp16x2, merged accumulator, 3 MFMA passes)
    gemm2<1><<<dim3(H_ENC / 128, BATCH / 128), 256, 0, stream>>>(xh, xl, W1Th, W1Tl, b1, h_hi, h_lo, nullptr, H_ENC, IN_PAD);
    gemm2<2><<<dim3(LATENT / 128, BATCH / 128), 256, 0, stream>>>(h_hi, h_lo, W2Th, W2Tl, b2, zh, zl, nullptr, LATENT, H_ENC);
    // distance pass: argmin folded into epilogue, bias = enorm, Part out (per-wave slots)
    gemm2<3><<<dim3(NUM_EMB / 128, BATCH / 128), 256, 0, stream>>>(zh, zl, eTh, eTl, enorm, nullptr, nullptr, Part, NUM_EMB, LATENT);
    // VQ finish (no atomics)
    vq2<<<BATCH / 4, 256, 0, stream>>>(Part, eTf, zh, zl, qb, lossPart);
    // decoder (bf16)
    gemm_bt<1><<<dim3(H_DEC / 128, BATCH / 128), 256, 0, stream>>>(qb, W3T, b3, h2, H_DEC, LATENT, H_DEC, H_DEC);
    gemm_bt<0><<<dim3(OUT_PAD / 128, BATCH / 128), 256, 0, stream>>>(h2, W4T, b4, out, OUT_PAD, H_DEC, OUT_DIM, OUT_DIM);
    reduce_loss<<<1, 256, 0, stream>>>(lossPart, out + (size_t)BATCH * OUT_DIM);

    (void)in_sizes; (void)n_in; (void)out_size; (void)ws_size;
}